// Round 20
// baseline (338.437 us; speedup 1.0000x reference)
//
#include <hip/hip_runtime.h>
#include <hip/hip_bf16.h>

typedef unsigned short u16;
typedef __attribute__((ext_vector_type(8))) short short8x;
typedef __attribute__((ext_vector_type(4))) unsigned short ushort4x;
typedef __attribute__((ext_vector_type(4))) float f32x4;
typedef __attribute__((ext_vector_type(2))) float f32x2;

__device__ __forceinline__ float bf2f(u16 u){
    unsigned int v = ((unsigned int)u) << 16;
    return __builtin_bit_cast(float, v);
}
__device__ __forceinline__ u16 f2bf(float f){
    __hip_bfloat16 h = __float2bfloat16(f);
    return __builtin_bit_cast(unsigned short, h);
}
// lgkmcnt-only barrier (T4): global loads stay in flight across phases.
__device__ __forceinline__ void lds_barrier(){
    asm volatile("s_waitcnt lgkmcnt(0)" ::: "memory");
    __builtin_amdgcn_s_barrier();
}

// ---- d_ws layout: identical to R12 ----
__global__ __launch_bounds__(256)
void prep(const float* __restrict__ qw, const float* __restrict__ kw,
          const float* __restrict__ vw, const float* __restrict__ pw,
          const float* __restrict__ dww,
          const float* __restrict__ qbn, const float* __restrict__ kbn,
          const float* __restrict__ vbn, const float* __restrict__ dbn,
          const float* __restrict__ pbn, void* __restrict__ ws)
{
    u16* W16 = (u16*)ws;
    float* WF = (float*)ws;
    const int t = (int)blockIdx.x * 256 + (int)threadIdx.x;
    if (t < 16384){
        W16[t]         = f2bf(qw[t]);
        W16[16384 + t] = f2bf(kw[t]);
        W16[32768 + t] = f2bf(vw[t]);
    }
    if (t < 65536) W16[49152 + t] = f2bf(pw[t]);
    if (t < 7168){
        const int k = t % 28, hc = t / 28;
        WF[57344 + t] = (k < 25) ? dww[hc * 25 + k] : 0.f;
    }
    if (t < 256){
        const int h = t >> 6, c = t & 63, base = h * 256;
        #pragma unroll
        for (int s = 0; s < 4; ++s){
            const float* bn = (s == 0 ? qbn : s == 1 ? kbn : s == 2 ? vbn : dbn);
            const float g = bn[base + c], b = bn[base + 64 + c];
            const float m = bn[base + 128 + c], v = bn[base + 192 + c];
            const float sc = g * rsqrtf(v + 1e-5f);
            WF[64512 + s * 512 + h * 128 + c * 2]     = sc;
            WF[64512 + s * 512 + h * 128 + c * 2 + 1] = b - m * sc;
        }
    }
    if (t < 256){
        const float g = pbn[t], b = pbn[256 + t], m = pbn[512 + t], v = pbn[768 + t];
        const float sc = g * rsqrtf(v + 1e-5f);
        WF[66560 + t * 2]     = sc;
        WF[66560 + t * 2 + 1] = b - m * sc;
    }
}

// R18 pair-block, TLP variant: 512 threads = 8 waves; waves 0-3 own window 0,
// waves 4-7 own window 1 (R15 per-window stage bodies, no w-loop).
// Same 73.7KB LDS -> 2 blocks/CU -> 16 waves/CU = 4 waves/SIMD (2x R18 TLP).
__global__ __launch_bounds__(512, 2)
void lwa_kernel(const float* __restrict__ x, const void* __restrict__ ws,
                float* __restrict__ y)
{
    const u16* W16 = (const u16*)ws;
    const float* WF = (const float*)ws;
    const u16* Wq = W16;
    const u16* Wk = W16 + 16384;
    const u16* Wv = W16 + 32768;
    const u16* Wp = W16 + 49152;

    __shared__ __align__(16) u16 S[2][4][64][72];   // [win][A,B,C,D]

    const int tid  = (int)threadIdx.x;
    const int u    = tid >> 8;          // window within pair
    const int t8   = tid & 255;
    const int lane = t8 & 63;
    const int wid  = t8 >> 6;           // wave within window-quad, 0..3
    const int g    = lane >> 4;
    const int r15  = lane & 15;

    u16 (*A)[72] = S[u][0];
    u16 (*B)[72] = S[u][1];
    u16 (*C)[72] = S[u][2];
    u16 (*D)[72] = S[u][3];

    // pair index with XCD-contiguous ranges
    const int ub    = (int)blockIdx.x;               // 0..2047
    const int pairi = (ub & 7) * 256 + (ub >> 3);
    const int bimg  = pairi >> 5, rem = pairi & 31;
    const int wy    = rem >> 2, jx = rem & 3;
    const size_t x_img = (size_t)bimg * (256 * 4096);
    const int pix_base = wy * 512 + jx * 16 + u * 8; // this window's 8-px span

    // head-0 chunk -> A[tok][ch] (per window; pair halves merge in L2)
    {
        const int c = t8 >> 2, qq = t8 & 3;
        const float* xp = x + x_img + (size_t)c * 4096 + pix_base;
        #pragma unroll
        for (int rr = 0; rr < 2; ++rr){
            const int py = qq * 2 + rr;
            f32x4 r0 = *(const f32x4*)(xp + py * 64);
            f32x4 r1 = *(const f32x4*)(xp + py * 64 + 4);
            #pragma unroll
            for (int px = 0; px < 4; ++px){
                A[py * 8 + px][c]     = f2bf(r0[px]);
                A[py * 8 + 4 + px][c] = f2bf(r1[px]);
            }
        }
    }

    f32x4 pacc[4][4];
    #pragma unroll
    for (int a = 0; a < 4; ++a)
        #pragma unroll
        for (int b = 0; b < 4; ++b)
            pacc[a][b] = (f32x4){0.f, 0.f, 0.f, 0.f};

    const int o0 = wid * 16 + g * 4;
    const int an = t8 >> 2, aj = t8 & 3, ac0 = aj * 16;   // S3 roles
    const int cdw = t8 & 63;                              // S2 role

    for (int i = 0; i < 4; ++i){
        // ---- batched S1 loads (stay in flight across the barrier) ----
        const int arow = (wid * 16 + r15) * 64 + g * 8;
        const short8x qa0 = *(const short8x*)(Wq + i * 4096 + arow);
        const short8x qa1 = *(const short8x*)(Wq + i * 4096 + arow + 32);
        const short8x ka0 = *(const short8x*)(Wk + i * 4096 + arow);
        const short8x ka1 = *(const short8x*)(Wk + i * 4096 + arow + 32);
        const short8x va0 = *(const short8x*)(Wv + i * 4096 + arow);
        const short8x va1 = *(const short8x*)(Wv + i * 4096 + arow + 32);
        f32x2 bq[4], bk[4], bv[4];
        #pragma unroll
        for (int r = 0; r < 4; ++r){
            bq[r] = *(const f32x2*)(WF + 64512 + i * 128 + (o0 + r) * 2);
            bk[r] = *(const f32x2*)(WF + 65024 + i * 128 + (o0 + r) * 2);
            bv[r] = *(const f32x2*)(WF + 65536 + i * 128 + (o0 + r) * 2);
        }
        lds_barrier();   // (1) A(feat i) ready; B/C/D free

        // ---- S1: fused q/k/v MFMA + BN ----
        #pragma unroll
        for (int tc = 0; tc < 4; ++tc){
            const short8x b0 = *(const short8x*)(&A[tc * 16 + r15][g * 8]);
            const short8x b1 = *(const short8x*)(&A[tc * 16 + r15][32 + g * 8]);
            f32x4 accq = (f32x4){0.f, 0.f, 0.f, 0.f};
            f32x4 acck = (f32x4){0.f, 0.f, 0.f, 0.f};
            f32x4 accv = (f32x4){0.f, 0.f, 0.f, 0.f};
            accq = __builtin_amdgcn_mfma_f32_16x16x32_bf16(qa0, b0, accq, 0, 0, 0);
            accq = __builtin_amdgcn_mfma_f32_16x16x32_bf16(qa1, b1, accq, 0, 0, 0);
            acck = __builtin_amdgcn_mfma_f32_16x16x32_bf16(ka0, b0, acck, 0, 0, 0);
            acck = __builtin_amdgcn_mfma_f32_16x16x32_bf16(ka1, b1, acck, 0, 0, 0);
            accv = __builtin_amdgcn_mfma_f32_16x16x32_bf16(va0, b0, accv, 0, 0, 0);
            accv = __builtin_amdgcn_mfma_f32_16x16x32_bf16(va1, b1, accv, 0, 0, 0);
            const int n2 = tc * 16 + r15;
            #pragma unroll
            for (int r = 0; r < 4; ++r){
                B[o0 + r][n2] = f2bf(accq[r] * bq[r][0] + bq[r][1]);   // q1 [ch][tok]
                C[o0 + r][n2] = f2bf(acck[r] * bk[r][0] + bk[r][1]);   // k  [ch][tok]
            }
            ushort4x pk;
            #pragma unroll
            for (int r = 0; r < 4; ++r) pk[r] = f2bf(accv[r] * bv[r][0] + bv[r][1]);
            *(ushort4x*)(&D[n2][o0]) = pk;                             // v  [tok][ch]
        }

        // ---- batched loads for S2/S3 ----
        f32x4 dwv[7];
        {
            const float* dwb = WF + 57344 + (i * 64 + cdw) * 28;
            #pragma unroll
            for (int k = 0; k < 7; ++k) dwv[k] = *(const f32x4*)(dwb + k * 4);
        }
        const f32x2 bd = *(const f32x2*)(WF + 66048 + i * 128 + cdw * 2);
        float pre[16];
        if (i < 3){
            const int py = an >> 3, px = an & 7;
            const float* xc = x + x_img + pix_base + py * 64 + px
                            + (size_t)((i + 1) * 64 + ac0) * 4096;
            #pragma unroll
            for (int e = 0; e < 8; ++e){
                pre[e]     = xc[(size_t)e * 4096];
                pre[8 + e] = xc[(size_t)(8 + e) * 4096];
            }
        }
        lds_barrier();   // (2) q1/k/v visible

        // ---- S2: dwconv 5x5 + BN; B(q1) -> A[tok][ch] ----
        {
            const int w2 = wid;
            float rin[6][8];
            #pragma unroll
            for (int rr = 0; rr < 6; ++rr){
                const int ry = 2 * w2 - 2 + rr;
                if (ry >= 0 && ry < 8){
                    short8x rv = *(const short8x*)(&B[cdw][ry * 8]);
                    #pragma unroll
                    for (int e = 0; e < 8; ++e) rin[rr][e] = bf2f((u16)rv[e]);
                } else {
                    #pragma unroll
                    for (int e = 0; e < 8; ++e) rin[rr][e] = 0.f;
                }
            }
            #pragma unroll
            for (int oy = 0; oy < 2; ++oy){
                #pragma unroll
                for (int px = 0; px < 8; ++px){
                    float acc = 0.f;
                    #pragma unroll
                    for (int ky = 0; ky < 5; ++ky){
                        #pragma unroll
                        for (int kx = 0; kx < 5; ++kx){
                            const int ix = px - 2 + kx;
                            const int w5 = ky * 5 + kx;
                            if (ix >= 0 && ix < 8)
                                acc += rin[oy + ky][ix] * dwv[w5 >> 2][w5 & 3];
                        }
                    }
                    A[(2 * w2 + oy) * 8 + px][cdw] = f2bf(acc * bd[0] + bd[1]);
                }
            }
        }
        lds_barrier();   // (3) qdw visible

        // ---- S3: attention; out -> B [tok][ch]; next feat -> A ----
        {
            const int n = an, c0 = ac0;
            short8x qb0 = *(const short8x*)(&A[n][c0]);
            short8x qb1 = *(const short8x*)(&A[n][c0 + 8]);
            short8x kb0 = *(const short8x*)(&C[n][c0]);
            short8x kb1 = *(const short8x*)(&C[n][c0 + 8]);
            short8x vb0 = *(const short8x*)(&D[n][c0]);
            short8x vb1 = *(const short8x*)(&D[n][c0 + 8]);
            float s[16];
            #pragma unroll
            for (int e = 0; e < 8; ++e){
                s[e]     = bf2f((u16)qb0[e]) * bf2f((u16)kb0[e]);
                s[8 + e] = bf2f((u16)qb1[e]) * bf2f((u16)kb1[e]);
            }
            float mx = s[0];
            #pragma unroll
            for (int e = 1; e < 16; ++e) mx = fmaxf(mx, s[e]);
            mx = fmaxf(mx, __shfl_xor(mx, 1));
            mx = fmaxf(mx, __shfl_xor(mx, 2));
            float sum = 0.f;
            #pragma unroll
            for (int e = 0; e < 16; ++e){ s[e] = __expf(s[e] - mx); sum += s[e]; }
            sum += __shfl_xor(sum, 1);
            sum += __shfl_xor(sum, 2);
            const float inv = 1.f / sum;
            float ov[16];
            #pragma unroll
            for (int e = 0; e < 8; ++e){
                ov[e]     = bf2f((u16)vb0[e]) * s[e] * inv;
                ov[8 + e] = bf2f((u16)vb1[e]) * s[8 + e] * inv;
            }
            short8x o0v, o1v;
            #pragma unroll
            for (int e = 0; e < 8; ++e){ o0v[e] = (short)f2bf(ov[e]); o1v[e] = (short)f2bf(ov[8 + e]); }
            *(short8x*)(&B[n][c0])     = o0v;
            *(short8x*)(&B[n][c0 + 8]) = o1v;
            if (i < 3){
                short8x f0v, f1v;
                #pragma unroll
                for (int e = 0; e < 8; ++e){
                    f0v[e] = (short)f2bf(pre[e]     + ov[e]);
                    f1v[e] = (short)f2bf(pre[8 + e] + ov[8 + e]);
                }
                *(short8x*)(&A[n][c0])     = f0v;
                *(short8x*)(&A[n][c0 + 8]) = f1v;
            }
        }

        // ---- batched p_w fragment loads for S4 ----
        short8x pf[8];
        #pragma unroll
        for (int rt = 0; rt < 4; ++rt)
            #pragma unroll
            for (int kk = 0; kk < 2; ++kk)
                pf[rt * 2 + kk] = *(const short8x*)(Wp + (size_t)(wid * 64 + rt * 16 + r15) * 256
                                                    + i * 64 + kk * 32 + g * 8);
        lds_barrier();   // (4) out(B) visible

        // ---- S4: projection pacc += p_w[:, 64i:64i+64] @ B^T ----
        #pragma unroll
        for (int rt = 0; rt < 4; ++rt){
            #pragma unroll
            for (int kk = 0; kk < 2; ++kk){
                #pragma unroll
                for (int tc = 0; tc < 4; ++tc){
                    short8x b = *(const short8x*)(&B[tc * 16 + r15][kk * 32 + g * 8]);
                    pacc[rt][tc] = __builtin_amdgcn_mfma_f32_16x16x32_bf16(pf[rt * 2 + kk], b,
                                                                           pacc[rt][tc], 0, 0, 0);
                }
            }
        }
    }

    // ---- epilogue: folded projection BN + fp32 store (pair halves merge) ----
    #pragma unroll
    for (int rt = 0; rt < 4; ++rt){
        f32x2 bp[4];
        #pragma unroll
        for (int r = 0; r < 4; ++r)
            bp[r] = *(const f32x2*)(WF + 66560 + (wid * 64 + rt * 16 + g * 4 + r) * 2);
        #pragma unroll
        for (int tc = 0; tc < 4; ++tc){
            #pragma unroll
            for (int r = 0; r < 4; ++r){
                const int o = wid * 64 + rt * 16 + g * 4 + r;
                const int n = tc * 16 + r15;
                const int py = n >> 3, px = n & 7;
                y[x_img + (size_t)o * 4096 + pix_base + py * 64 + px]
                    = pacc[rt][tc][r] * bp[r][0] + bp[r][1];
            }
        }
    }
}

extern "C" void kernel_launch(void* const* d_in, const int* in_sizes, int n_in,
                              void* d_out, int out_size, void* d_ws, size_t ws_size,
                              hipStream_t stream) {
    const float* x    = (const float*)d_in[0];
    const float* q_w  = (const float*)d_in[1];
    const float* q_bn = (const float*)d_in[2];
    const float* k_w  = (const float*)d_in[3];
    const float* k_bn = (const float*)d_in[4];
    const float* v_w  = (const float*)d_in[5];
    const float* v_bn = (const float*)d_in[6];
    const float* dw_w = (const float*)d_in[7];
    const float* dw_bn= (const float*)d_in[8];
    const float* p_w  = (const float*)d_in[9];
    const float* p_bn = (const float*)d_in[10];
    float* yout = (float*)d_out;

    prep<<<dim3(256), dim3(256), 0, stream>>>(q_w, k_w, v_w, p_w, dw_w,
                                              q_bn, k_bn, v_bn, dw_bn, p_bn, d_ws);
    lwa_kernel<<<dim3(2048), dim3(512), 0, stream>>>(x, d_ws, yout);
}

// Round 21
// 282.974 us; speedup vs baseline: 1.1960x; 1.1960x over previous
//
#include <hip/hip_runtime.h>
#include <hip/hip_bf16.h>

typedef unsigned short u16;
typedef __attribute__((ext_vector_type(8))) short short8x;
typedef __attribute__((ext_vector_type(4))) unsigned short ushort4x;
typedef __attribute__((ext_vector_type(4))) float f32x4;
typedef __attribute__((ext_vector_type(2))) float f32x2;

__device__ __forceinline__ float bf2f(u16 u){
    unsigned int v = ((unsigned int)u) << 16;
    return __builtin_bit_cast(float, v);
}
__device__ __forceinline__ u16 f2bf(float f){
    __hip_bfloat16 h = __float2bfloat16(f);
    return __builtin_bit_cast(unsigned short, h);
}
// lgkmcnt-only barrier (T4): global loads stay in flight across phases.
__device__ __forceinline__ void lds_barrier(){
    asm volatile("s_waitcnt lgkmcnt(0)" ::: "memory");
    __builtin_amdgcn_s_barrier();
}

// ---- d_ws layout: identical to R12 ----
__global__ __launch_bounds__(256)
void prep(const float* __restrict__ qw, const float* __restrict__ kw,
          const float* __restrict__ vw, const float* __restrict__ pw,
          const float* __restrict__ dww,
          const float* __restrict__ qbn, const float* __restrict__ kbn,
          const float* __restrict__ vbn, const float* __restrict__ dbn,
          const float* __restrict__ pbn, void* __restrict__ ws)
{
    u16* W16 = (u16*)ws;
    float* WF = (float*)ws;
    const int t = (int)blockIdx.x * 256 + (int)threadIdx.x;
    if (t < 16384){
        W16[t]         = f2bf(qw[t]);
        W16[16384 + t] = f2bf(kw[t]);
        W16[32768 + t] = f2bf(vw[t]);
    }
    if (t < 65536) W16[49152 + t] = f2bf(pw[t]);
    if (t < 7168){
        const int k = t % 28, hc = t / 28;
        WF[57344 + t] = (k < 25) ? dww[hc * 25 + k] : 0.f;
    }
    if (t < 256){
        const int h = t >> 6, c = t & 63, base = h * 256;
        #pragma unroll
        for (int s = 0; s < 4; ++s){
            const float* bn = (s == 0 ? qbn : s == 1 ? kbn : s == 2 ? vbn : dbn);
            const float g = bn[base + c], b = bn[base + 64 + c];
            const float m = bn[base + 128 + c], v = bn[base + 192 + c];
            const float sc = g * rsqrtf(v + 1e-5f);
            WF[64512 + s * 512 + h * 128 + c * 2]     = sc;
            WF[64512 + s * 512 + h * 128 + c * 2 + 1] = b - m * sc;
        }
    }
    if (t < 256){
        const float g = pbn[t], b = pbn[256 + t], m = pbn[512 + t], v = pbn[768 + t];
        const float sc = g * rsqrtf(v + 1e-5f);
        WF[66560 + t * 2]     = sc;
        WF[66560 + t * 2 + 1] = b - m * sc;
    }
}

// R18 pair-block core + (1) s_setprio around MFMA clusters (2 co-resident
// blocks drift into different phases -> scheduler has role-diverse waves),
// (2) pre-loads hoisted one phase earlier (2 phases of HBM-latency cover).
__global__ __launch_bounds__(256, 2)
void lwa_kernel(const float* __restrict__ x, const void* __restrict__ ws,
                float* __restrict__ y)
{
    const u16* W16 = (const u16*)ws;
    const float* WF = (const float*)ws;
    const u16* Wq = W16;
    const u16* Wk = W16 + 16384;
    const u16* Wv = W16 + 32768;
    const u16* Wp = W16 + 49152;

    __shared__ __align__(16) u16 S[2][4][64][72];   // [win][A,B,C,D]

    const int tid  = (int)threadIdx.x;
    const int lane = tid & 63;
    const int wid  = tid >> 6;
    const int g    = lane >> 4;
    const int r15  = lane & 15;

    // pair index with XCD-contiguous ranges
    const int ub    = (int)blockIdx.x;               // 0..2047
    const int pairi = (ub & 7) * 256 + (ub >> 3);
    const int bimg  = pairi >> 5, rem = pairi & 31;
    const int wy    = rem >> 2, jx = rem & 3;
    const size_t x_img = (size_t)bimg * (256 * 4096);
    const int pixp  = wy * 512 + jx * 16;            // base of the pair's 16-px span

    // head-0 chunk -> A of both windows
    {
        const int c = tid >> 2, qq = tid & 3;
        const float* xp = x + x_img + (size_t)c * 4096 + pixp;
        #pragma unroll
        for (int rr = 0; rr < 2; ++rr){
            const int py = qq * 2 + rr;
            f32x4 r0 = *(const f32x4*)(xp + py * 64);
            f32x4 r1 = *(const f32x4*)(xp + py * 64 + 4);
            f32x4 r2 = *(const f32x4*)(xp + py * 64 + 8);
            f32x4 r3 = *(const f32x4*)(xp + py * 64 + 12);
            #pragma unroll
            for (int px = 0; px < 4; ++px){
                S[0][0][py * 8 + px][c]     = f2bf(r0[px]);
                S[0][0][py * 8 + 4 + px][c] = f2bf(r1[px]);
                S[1][0][py * 8 + px][c]     = f2bf(r2[px]);
                S[1][0][py * 8 + 4 + px][c] = f2bf(r3[px]);
            }
        }
    }

    f32x4 pacc[2][4][4];
    #pragma unroll
    for (int w = 0; w < 2; ++w)
        #pragma unroll
        for (int a = 0; a < 4; ++a)
            #pragma unroll
            for (int b = 0; b < 4; ++b)
                pacc[w][a][b] = (f32x4){0.f, 0.f, 0.f, 0.f};

    const int o0 = wid * 16 + g * 4;
    const int an = tid >> 2, aj = tid & 3, ac0 = aj * 16;   // S3 roles
    const int cdw = tid & 63;                               // S2 role

    for (int i = 0; i < 4; ++i){
        // ---- hoisted S1 loads (once per block, both windows) ----
        const int arow = (wid * 16 + r15) * 64 + g * 8;
        const short8x qa0 = *(const short8x*)(Wq + i * 4096 + arow);
        const short8x qa1 = *(const short8x*)(Wq + i * 4096 + arow + 32);
        const short8x ka0 = *(const short8x*)(Wk + i * 4096 + arow);
        const short8x ka1 = *(const short8x*)(Wk + i * 4096 + arow + 32);
        const short8x va0 = *(const short8x*)(Wv + i * 4096 + arow);
        const short8x va1 = *(const short8x*)(Wv + i * 4096 + arow + 32);
        f32x2 bq[4], bk[4], bv[4];
        #pragma unroll
        for (int r = 0; r < 4; ++r){
            bq[r] = *(const f32x2*)(WF + 64512 + i * 128 + (o0 + r) * 2);
            bk[r] = *(const f32x2*)(WF + 65024 + i * 128 + (o0 + r) * 2);
            bv[r] = *(const f32x2*)(WF + 65536 + i * 128 + (o0 + r) * 2);
        }
        // ---- pre loads hoisted: issued here, consumed after barrier (3) ----
        float pre[2][16];
        if (i < 3){
            const int py = an >> 3, px = an & 7;
            const float* xc = x + x_img + pixp + py * 64 + px
                            + (size_t)((i + 1) * 64 + ac0) * 4096;
            #pragma unroll
            for (int e = 0; e < 8; ++e){
                pre[0][e]     = xc[(size_t)e * 4096];
                pre[1][e]     = xc[(size_t)e * 4096 + 8];
                pre[0][8 + e] = xc[(size_t)(8 + e) * 4096];
                pre[1][8 + e] = xc[(size_t)(8 + e) * 4096 + 8];
            }
        }
        lds_barrier();   // (1) feat ready; B/C/D free

        // ---- S1: fused q/k/v MFMA + BN, both windows (weights reused) ----
        __builtin_amdgcn_s_setprio(1);
        #pragma unroll
        for (int w = 0; w < 2; ++w){
            u16 (*A)[72] = S[w][0];
            u16 (*B)[72] = S[w][1];
            u16 (*C)[72] = S[w][2];
            u16 (*D)[72] = S[w][3];
            #pragma unroll
            for (int tc = 0; tc < 4; ++tc){
                const short8x b0 = *(const short8x*)(&A[tc * 16 + r15][g * 8]);
                const short8x b1 = *(const short8x*)(&A[tc * 16 + r15][32 + g * 8]);
                f32x4 accq = (f32x4){0.f, 0.f, 0.f, 0.f};
                f32x4 acck = (f32x4){0.f, 0.f, 0.f, 0.f};
                f32x4 accv = (f32x4){0.f, 0.f, 0.f, 0.f};
                accq = __builtin_amdgcn_mfma_f32_16x16x32_bf16(qa0, b0, accq, 0, 0, 0);
                accq = __builtin_amdgcn_mfma_f32_16x16x32_bf16(qa1, b1, accq, 0, 0, 0);
                acck = __builtin_amdgcn_mfma_f32_16x16x32_bf16(ka0, b0, acck, 0, 0, 0);
                acck = __builtin_amdgcn_mfma_f32_16x16x32_bf16(ka1, b1, acck, 0, 0, 0);
                accv = __builtin_amdgcn_mfma_f32_16x16x32_bf16(va0, b0, accv, 0, 0, 0);
                accv = __builtin_amdgcn_mfma_f32_16x16x32_bf16(va1, b1, accv, 0, 0, 0);
                const int n2 = tc * 16 + r15;
                #pragma unroll
                for (int r = 0; r < 4; ++r){
                    B[o0 + r][n2] = f2bf(accq[r] * bq[r][0] + bq[r][1]);   // q1 [ch][tok]
                    C[o0 + r][n2] = f2bf(acck[r] * bk[r][0] + bk[r][1]);   // k  [ch][tok]
                }
                ushort4x pk;
                #pragma unroll
                for (int r = 0; r < 4; ++r) pk[r] = f2bf(accv[r] * bv[r][0] + bv[r][1]);
                *(ushort4x*)(&D[n2][o0]) = pk;                             // v  [tok][ch]
            }
        }
        __builtin_amdgcn_s_setprio(0);

        // ---- hoisted S2 loads ----
        f32x4 dwv[7];
        {
            const float* dwb = WF + 57344 + (i * 64 + cdw) * 28;
            #pragma unroll
            for (int k = 0; k < 7; ++k) dwv[k] = *(const f32x4*)(dwb + k * 4);
        }
        const f32x2 bd = *(const f32x2*)(WF + 66048 + i * 128 + cdw * 2);
        lds_barrier();   // (2) q1/k/v visible

        // ---- S2: dwconv 5x5 + BN, both windows; B(q1) -> A[tok][ch] ----
        #pragma unroll
        for (int w = 0; w < 2; ++w){
            u16 (*A)[72] = S[w][0];
            u16 (*B)[72] = S[w][1];
            float rin[6][8];
            #pragma unroll
            for (int rr = 0; rr < 6; ++rr){
                const int ry = 2 * wid - 2 + rr;
                if (ry >= 0 && ry < 8){
                    short8x rv = *(const short8x*)(&B[cdw][ry * 8]);
                    #pragma unroll
                    for (int e = 0; e < 8; ++e) rin[rr][e] = bf2f((u16)rv[e]);
                } else {
                    #pragma unroll
                    for (int e = 0; e < 8; ++e) rin[rr][e] = 0.f;
                }
            }
            #pragma unroll
            for (int oy = 0; oy < 2; ++oy){
                #pragma unroll
                for (int px = 0; px < 8; ++px){
                    float acc = 0.f;
                    #pragma unroll
                    for (int ky = 0; ky < 5; ++ky){
                        #pragma unroll
                        for (int kx = 0; kx < 5; ++kx){
                            const int ix = px - 2 + kx;
                            const int w5 = ky * 5 + kx;
                            if (ix >= 0 && ix < 8)
                                acc += rin[oy + ky][ix] * dwv[w5 >> 2][w5 & 3];
                        }
                    }
                    A[(2 * wid + oy) * 8 + px][cdw] = f2bf(acc * bd[0] + bd[1]);
                }
            }
        }
        lds_barrier();   // (3) qdw visible

        // ---- S3: attention, both windows; out -> B; next feat -> A ----
        #pragma unroll
        for (int w = 0; w < 2; ++w){
            u16 (*A)[72] = S[w][0];
            u16 (*B)[72] = S[w][1];
            u16 (*C)[72] = S[w][2];
            u16 (*D)[72] = S[w][3];
            const int n = an, c0 = ac0;
            short8x qb0 = *(const short8x*)(&A[n][c0]);
            short8x qb1 = *(const short8x*)(&A[n][c0 + 8]);
            short8x kb0 = *(const short8x*)(&C[n][c0]);
            short8x kb1 = *(const short8x*)(&C[n][c0 + 8]);
            short8x vb0 = *(const short8x*)(&D[n][c0]);
            short8x vb1 = *(const short8x*)(&D[n][c0 + 8]);
            float s[16];
            #pragma unroll
            for (int e = 0; e < 8; ++e){
                s[e]     = bf2f((u16)qb0[e]) * bf2f((u16)kb0[e]);
                s[8 + e] = bf2f((u16)qb1[e]) * bf2f((u16)kb1[e]);
            }
            float mx = s[0];
            #pragma unroll
            for (int e = 1; e < 16; ++e) mx = fmaxf(mx, s[e]);
            mx = fmaxf(mx, __shfl_xor(mx, 1));
            mx = fmaxf(mx, __shfl_xor(mx, 2));
            float sum = 0.f;
            #pragma unroll
            for (int e = 0; e < 16; ++e){ s[e] = __expf(s[e] - mx); sum += s[e]; }
            sum += __shfl_xor(sum, 1);
            sum += __shfl_xor(sum, 2);
            const float inv = 1.f / sum;
            float ov[16];
            #pragma unroll
            for (int e = 0; e < 8; ++e){
                ov[e]     = bf2f((u16)vb0[e]) * s[e] * inv;
                ov[8 + e] = bf2f((u16)vb1[e]) * s[8 + e] * inv;
            }
            short8x o0v, o1v;
            #pragma unroll
            for (int e = 0; e < 8; ++e){ o0v[e] = (short)f2bf(ov[e]); o1v[e] = (short)f2bf(ov[8 + e]); }
            *(short8x*)(&B[n][c0])     = o0v;
            *(short8x*)(&B[n][c0 + 8]) = o1v;
            if (i < 3){
                short8x f0v, f1v;
                #pragma unroll
                for (int e = 0; e < 8; ++e){
                    f0v[e] = (short)f2bf(pre[w][e]     + ov[e]);
                    f1v[e] = (short)f2bf(pre[w][8 + e] + ov[8 + e]);
                }
                *(short8x*)(&A[n][c0])     = f0v;
                *(short8x*)(&A[n][c0 + 8]) = f1v;
            }
        }

        // ---- hoisted p_w fragments (once, both windows) ----
        short8x pf[8];
        #pragma unroll
        for (int rt = 0; rt < 4; ++rt)
            #pragma unroll
            for (int kk = 0; kk < 2; ++kk)
                pf[rt * 2 + kk] = *(const short8x*)(Wp + (size_t)(wid * 64 + rt * 16 + r15) * 256
                                                    + i * 64 + kk * 32 + g * 8);
        lds_barrier();   // (4) out(B) visible

        // ---- S4: projection, both windows ----
        __builtin_amdgcn_s_setprio(1);
        #pragma unroll
        for (int w = 0; w < 2; ++w){
            u16 (*B)[72] = S[w][1];
            #pragma unroll
            for (int rt = 0; rt < 4; ++rt){
                #pragma unroll
                for (int kk = 0; kk < 2; ++kk){
                    #pragma unroll
                    for (int tc = 0; tc < 4; ++tc){
                        short8x b = *(const short8x*)(&B[tc * 16 + r15][kk * 32 + g * 8]);
                        pacc[w][rt][tc] = __builtin_amdgcn_mfma_f32_16x16x32_bf16(pf[rt * 2 + kk], b,
                                                                                  pacc[w][rt][tc], 0, 0, 0);
                    }
                }
            }
        }
        __builtin_amdgcn_s_setprio(0);
    }

    // ---- epilogue: folded BN + paired full-line fp32 stores ----
    #pragma unroll
    for (int rt = 0; rt < 4; ++rt){
        f32x2 bp[4];
        #pragma unroll
        for (int r = 0; r < 4; ++r)
            bp[r] = *(const f32x2*)(WF + 66560 + (wid * 64 + rt * 16 + g * 4 + r) * 2);
        #pragma unroll
        for (int tc = 0; tc < 4; ++tc){
            #pragma unroll
            for (int r = 0; r < 4; ++r){
                const int o = wid * 64 + rt * 16 + g * 4 + r;
                const int n = tc * 16 + r15;
                const int py = n >> 3, px = n & 7;
                const size_t base = x_img + (size_t)o * 4096 + pixp + py * 64 + px;
                y[base]     = pacc[0][rt][tc][r] * bp[r][0] + bp[r][1];
                y[base + 8] = pacc[1][rt][tc][r] * bp[r][0] + bp[r][1];
            }
        }
    }
}

extern "C" void kernel_launch(void* const* d_in, const int* in_sizes, int n_in,
                              void* d_out, int out_size, void* d_ws, size_t ws_size,
                              hipStream_t stream) {
    const float* x    = (const float*)d_in[0];
    const float* q_w  = (const float*)d_in[1];
    const float* q_bn = (const float*)d_in[2];
    const float* k_w  = (const float*)d_in[3];
    const float* k_bn = (const float*)d_in[4];
    const float* v_w  = (const float*)d_in[5];
    const float* v_bn = (const float*)d_in[6];
    const float* dw_w = (const float*)d_in[7];
    const float* dw_bn= (const float*)d_in[8];
    const float* p_w  = (const float*)d_in[9];
    const float* p_bn = (const float*)d_in[10];
    float* yout = (float*)d_out;

    prep<<<dim3(256), dim3(256), 0, stream>>>(q_w, k_w, v_w, p_w, dw_w,
                                              q_bn, k_bn, v_bn, dw_bn, p_bn, d_ws);
    lwa_kernel<<<dim3(2048), dim3(256), 0, stream>>>(x, d_ws, yout);
}